// Round 19
// baseline (350.183 us; speedup 1.0000x reference)
//
#include <hip/hip_runtime.h>

#define N_NODES 20000
#define N_PAD   20480   // 160 row-blocks of 128 -> exact 8-XCD partition (20 each)
#define N_EDGES 320000
#define F_IN 512
#define F_OUT 1024
#define N_GRAPHS 64
#define ESTRIDE 64      // fixed edge slots per node (P(deg>63) ~ 1e-20 for Poisson(16))

typedef __attribute__((ext_vector_type(8))) short bf16x8;
typedef __attribute__((ext_vector_type(16))) float f32x16;
typedef __attribute__((ext_vector_type(8))) unsigned short ushort8v;

static __device__ __forceinline__ unsigned short f2bf(float f) {
    unsigned int u = __float_as_uint(f);
    u = (u + 0x7fff + ((u >> 16) & 1)) >> 16;   // RNE
    return (unsigned short)u;
}
static __device__ __forceinline__ float bf2f(unsigned short s) {
    return __uint_as_float(((unsigned int)s) << 16);
}

// ---------------- setup: deg/cursor init + out zero + gstart ----------------
__global__ void k_setup(float* deg, int* cursor, float* out,
                        const int* __restrict__ batch, int* gstart) {
    int i = blockIdx.x * 256 + threadIdx.x;   // grid covers 65536
    if (i < N_NODES) { deg[i] = 1.0f; cursor[i] = 0; }
    if (i < N_GRAPHS * F_OUT) out[i] = 0.f;
    if (i <= N_GRAPHS) {
        if (i == N_GRAPHS) gstart[i] = N_NODES;
        else {
            int lo = 0, hi = N_NODES;
            while (lo < hi) {
                int mid = (lo + hi) >> 1;
                if (batch[mid] < i) lo = mid + 1; else hi = mid;
            }
            gstart[i] = lo;
        }
    }
}

// ---------------- fat pre-pass: deg atomics + W transposes + x conversion ----------------
#define NB_E    ((N_EDGES + 255) / 256)                 // 1250
#define NB_WT   ((F_OUT / 32) * (F_IN / 32 + F_OUT / 32)) // 32*48 = 1536
#define NB_CX   (N_PAD * (F_IN / 8) / 256)              // 5120
__global__ __launch_bounds__(256) void k_pre(const int* __restrict__ dst,
                                             const float* __restrict__ ew,
                                             float* deg,
                                             const float* __restrict__ W1,
                                             unsigned short* __restrict__ Wt1,
                                             const float* __restrict__ W2,
                                             unsigned short* __restrict__ Wt2,
                                             const float* __restrict__ x,
                                             unsigned short* __restrict__ xb) {
    __shared__ float tile[32][33];
    const int bid = blockIdx.x;
    if (bid < NB_E) {
        int e = bid * 256 + threadIdx.x;
        if (e < N_EDGES) atomicAdd(&deg[dst[e]], ew[e]);
    } else if (bid < NB_E + NB_WT) {
        int cid = bid - NB_E;
        int by = cid >> 5;          // 0..47
        int n0 = (cid & 31) * 32;
        const float* W; unsigned short* Wt; int K, k0;
        if (by < F_IN / 32) { W = W1; Wt = Wt1; K = F_IN;  k0 = by * 32; }
        else                { W = W2; Wt = Wt2; K = F_OUT; k0 = (by - F_IN / 32) * 32; }
        int tx = threadIdx.x & 31;
        int ty = threadIdx.x >> 5;
#pragma unroll
        for (int i = 0; i < 32; i += 8)
            tile[ty + i][tx] = W[(size_t)(k0 + ty + i) * F_OUT + n0 + tx];
        __syncthreads();
#pragma unroll
        for (int i = 0; i < 32; i += 8)
            Wt[(size_t)(n0 + ty + i) * K + k0 + tx] = f2bf(tile[tx][ty + i]);
    } else {
        int idx = (bid - NB_E - NB_WT) * 256 + threadIdx.x;  // one thread = 8 cols
        int row = idx >> 6;
        int c8 = (idx & 63) * 8;
        if (row >= N_PAD) return;
        ushort8v v;
        if (row < N_NODES) {
            const float* p = &x[(size_t)row * F_IN + c8];
#pragma unroll
            for (int i = 0; i < 8; i++) v[i] = f2bf(p[i]);
        } else {
#pragma unroll
            for (int i = 0; i < 8; i++) v[i] = 0;
        }
        *(ushort8v*)&xb[(size_t)row * F_IN + c8] = v;
    }
}

// ---------------- direct-slot packed edge table: csre[d*64+pos] = (w_bf16<<16)|src ----------------
__global__ void k_fill(const int* __restrict__ src, const int* __restrict__ dst,
                       const float* __restrict__ ew, const float* __restrict__ deg,
                       int* cursor, unsigned int* __restrict__ csre) {
    int e = blockIdx.x * 256 + threadIdx.x;
    if (e < N_EDGES) {
        int d = dst[e], s = src[e];
        int pos = atomicAdd(&cursor[d], 1);
        if (pos < ESTRIDE) {
            float w = rsqrtf(deg[s]) * ew[e] * rsqrtf(deg[d]);
            csre[d * ESTRIDE + pos] = ((unsigned int)f2bf(w) << 16) | (unsigned int)s;
        }
    }
}

// ---------------- layer-1 slab aggregation: 1 wave = 8 nodes x one 64-col slab ----------------
// 4x-unrolled edge loop; packed 4B metadata -> one 16B dwordx4 per 4-edge group.
// Also zero-fills pad rows (GEMM1 reads them).
__global__ __launch_bounds__(64) void k_aggr_slab(const unsigned short* __restrict__ xin,
                                                  const float* __restrict__ deg,
                                                  const int* __restrict__ cursor,
                                                  const unsigned int* __restrict__ csre,
                                                  unsigned short* __restrict__ outp,
                                                  int F) {
    const int bid = blockIdx.x;
    const int slab = bid & 7;
    const int ng = bid >> 3;
    const int lane = threadIdx.x;
    const int n = ng * 8 + (lane >> 3);
    const int c = slab * 64 + (lane & 7) * 8;

    if (n >= N_NODES) {
        ushort8v z;
#pragma unroll
        for (int i = 0; i < 8; i++) z[i] = 0;
        *(ushort8v*)&outp[(size_t)n * F + c] = z;
        return;
    }

    const float di = rsqrtf(deg[n]);
    const float wself = di * di;
    float a[8];
    {
        ushort8v v = *(const ushort8v*)&xin[(size_t)n * F + c];
#pragma unroll
        for (int i = 0; i < 8; i++) a[i] = bf2f(v[i]) * wself;
    }

    const unsigned int* ce = csre + (size_t)n * ESTRIDE;
    const int cnt = min(cursor[n], ESTRIDE);
    int j = 0;
    for (; j + 4 <= cnt; j += 4) {
        uint4 m = *(const uint4*)&ce[j];
        ushort8v u0 = *(const ushort8v*)&xin[(size_t)(m.x & 0xFFFF) * F + c];
        ushort8v u1 = *(const ushort8v*)&xin[(size_t)(m.y & 0xFFFF) * F + c];
        ushort8v u2 = *(const ushort8v*)&xin[(size_t)(m.z & 0xFFFF) * F + c];
        ushort8v u3 = *(const ushort8v*)&xin[(size_t)(m.w & 0xFFFF) * F + c];
        float w0 = bf2f((unsigned short)(m.x >> 16));
        float w1 = bf2f((unsigned short)(m.y >> 16));
        float w2 = bf2f((unsigned short)(m.z >> 16));
        float w3 = bf2f((unsigned short)(m.w >> 16));
#pragma unroll
        for (int i = 0; i < 8; i++) {
            a[i] += w0 * bf2f(u0[i]);
            a[i] += w1 * bf2f(u1[i]);
            a[i] += w2 * bf2f(u2[i]);
            a[i] += w3 * bf2f(u3[i]);
        }
    }
    for (; j < cnt; j++) {
        unsigned int m = ce[j];
        float w = bf2f((unsigned short)(m >> 16));
        ushort8v u = *(const ushort8v*)&xin[(size_t)(m & 0xFFFF) * F + c];
#pragma unroll
        for (int i = 0; i < 8; i++) a[i] += w * bf2f(u[i]);
    }

    ushort8v r;
#pragma unroll
    for (int i = 0; i < 8; i++) r[i] = f2bf(a[i]);
    *(ushort8v*)&outp[(size_t)n * F + c] = r;
}

// ---------------- layer-2 DUAL-PASS aggregation + bias + relu ----------------
// One wave handles its (8-node, 64-col slab) for BOTH 512-col passes: metadata
// loads halved, per-wave fixed cost halved, 4 gathers in flight (2 edges x 2 passes).
// Grid covers only real nodes (pool never reads pad rows).
__global__ __launch_bounds__(64) void k_aggr_dual(const unsigned short* __restrict__ xin,
                                                  const float* __restrict__ deg,
                                                  const int* __restrict__ cursor,
                                                  const unsigned int* __restrict__ csre,
                                                  const float* __restrict__ bias,
                                                  unsigned short* __restrict__ outp) {
    const int bid = blockIdx.x;
    const int slab = bid & 7;
    const int ng = bid >> 3;                       // 0..2499, all real
    const int lane = threadIdx.x;
    const int n = ng * 8 + (lane >> 3);
    const int c0 = slab * 64 + (lane & 7) * 8;     // pass-0 col
    const int c1 = c0 + 512;                       // pass-1 col

    const float di = rsqrtf(deg[n]);
    const float wself = di * di;
    float a[16];
    {
        ushort8v v0 = *(const ushort8v*)&xin[(size_t)n * F_OUT + c0];
        ushort8v v1 = *(const ushort8v*)&xin[(size_t)n * F_OUT + c1];
#pragma unroll
        for (int i = 0; i < 8; i++) {
            a[i]     = bf2f(v0[i]) * wself;
            a[8 + i] = bf2f(v1[i]) * wself;
        }
    }

    const unsigned int* ce = csre + (size_t)n * ESTRIDE;
    const int cnt = min(cursor[n], ESTRIDE);
    int j = 0;
    for (; j + 2 <= cnt; j += 2) {
        uint2 m = *(const uint2*)&ce[j];           // 2 packed edges, 8B
        size_t r0 = (size_t)(m.x & 0xFFFF) * F_OUT;
        size_t r1 = (size_t)(m.y & 0xFFFF) * F_OUT;
        ushort8v u00 = *(const ushort8v*)&xin[r0 + c0];
        ushort8v u01 = *(const ushort8v*)&xin[r0 + c1];
        ushort8v u10 = *(const ushort8v*)&xin[r1 + c0];
        ushort8v u11 = *(const ushort8v*)&xin[r1 + c1];
        float w0 = bf2f((unsigned short)(m.x >> 16));
        float w1 = bf2f((unsigned short)(m.y >> 16));
#pragma unroll
        for (int i = 0; i < 8; i++) {
            a[i]     += w0 * bf2f(u00[i]);
            a[8 + i] += w0 * bf2f(u01[i]);
            a[i]     += w1 * bf2f(u10[i]);
            a[8 + i] += w1 * bf2f(u11[i]);
        }
    }
    if (j < cnt) {
        unsigned int m = ce[j];
        size_t r0 = (size_t)(m & 0xFFFF) * F_OUT;
        float w = bf2f((unsigned short)(m >> 16));
        ushort8v u0 = *(const ushort8v*)&xin[r0 + c0];
        ushort8v u1 = *(const ushort8v*)&xin[r0 + c1];
#pragma unroll
        for (int i = 0; i < 8; i++) {
            a[i]     += w * bf2f(u0[i]);
            a[8 + i] += w * bf2f(u1[i]);
        }
    }

    ushort8v r0v, r1v;
#pragma unroll
    for (int i = 0; i < 8; i++) {
        r0v[i] = f2bf(fmaxf(a[i]     + bias[c0 + i], 0.f));
        r1v[i] = f2bf(fmaxf(a[8 + i] + bias[c1 + i], 0.f));
    }
    *(ushort8v*)&outp[(size_t)n * F_OUT + c0] = r0v;
    *(ushort8v*)&outp[(size_t)n * F_OUT + c1] = r1v;
}

// ---------------- bf16 MFMA GEMM (32x32x16, BK=64): C_bf16[N_PAD,1024] = A @ Bt^T ----------------
// xcd=bid&7 owns row-blocks [xcd*20, xcd*20+20), col-block fastest -> A-slice L2-resident.
// BK=64: 32 MFMA + 16 ds_read between barriers. LDS: 8 granules/row, swizzle g^(r&7);
// 1024 granules staged in 4 iterations of 256 threads.
__global__ __launch_bounds__(256) void k_gemm_bf16(const unsigned short* __restrict__ A,
                                                   const unsigned short* __restrict__ Bt,
                                                   unsigned short* __restrict__ C, int K,
                                                   const float* __restrict__ bias, int act) {
    __shared__ short As[128 * 64];   // 16 KB
    __shared__ short Bs[128 * 64];   // 16 KB
    const int bid = blockIdx.x;
    const int xcd = bid & 7;
    const int i2 = bid >> 3;                 // 0..159
    const int colb = i2 & 7;
    const int rowb = xcd * 20 + (i2 >> 3);   // exact partition: 8 XCD x 20 row-blocks
    const int row0 = rowb * 128;
    const int col0 = colb * 128;

    const int tid = threadIdx.x;
    const int lane = tid & 63;
    const int wave = tid >> 6;
    const int wm = wave >> 1, wn = wave & 1;
    const int l5 = lane & 31;
    const int kh = lane >> 5;                // k-half within a 16-k MFMA step

    f32x16 acc[2][2] = {};

    for (int k0 = 0; k0 < K; k0 += 64) {
#pragma unroll
        for (int it = 0; it < 4; it++) {       // 4*256 = 1024 granules per tile
            int idx = it * 256 + tid;          // granule id 0..1023 (lane-linear dest)
            int r = idx >> 3;                  // row 0..127
            int g = (idx & 7) ^ (r & 7);       // swizzled source k-chunk
            const unsigned short* ga = &A[(size_t)(row0 + r) * K + k0 + g * 8];
            __builtin_amdgcn_global_load_lds(
                (const __attribute__((address_space(1))) void*)ga,
                (__attribute__((address_space(3))) void*)&As[idx * 8], 16, 0, 0);
            const unsigned short* gb = &Bt[(size_t)(col0 + r) * K + k0 + g * 8];
            __builtin_amdgcn_global_load_lds(
                (const __attribute__((address_space(1))) void*)gb,
                (__attribute__((address_space(3))) void*)&Bs[idx * 8], 16, 0, 0);
        }
        __syncthreads();

#pragma unroll
        for (int kk = 0; kk < 4; kk++) {
            const int g = kk * 2 + kh;         // this lane's k-chunk for MFMA step kk
            bf16x8 af[2], bfr[2];
#pragma unroll
            for (int i = 0; i < 2; i++) {
                int ar = wm * 64 + i * 32 + l5;
                af[i] = *(const bf16x8*)&As[(ar * 8 + (g ^ (ar & 7))) * 8];
            }
#pragma unroll
            for (int j = 0; j < 2; j++) {
                int br = wn * 64 + j * 32 + l5;
                bfr[j] = *(const bf16x8*)&Bs[(br * 8 + (g ^ (br & 7))) * 8];
            }
#pragma unroll
            for (int i = 0; i < 2; i++)
#pragma unroll
                for (int j = 0; j < 2; j++)
                    acc[i][j] = __builtin_amdgcn_mfma_f32_32x32x16_bf16(
                        af[i], bfr[j], acc[i][j], 0, 0, 0);
        }
        __syncthreads();
    }

    // C/D: col=lane&31, row=(reg&3)+8*(reg>>2)+4*(lane>>5)  [m74/m101]
#pragma unroll
    for (int i = 0; i < 2; i++) {
#pragma unroll
        for (int j = 0; j < 2; j++) {
            int rbase = row0 + wm * 64 + i * 32 + kh * 4;
            int c = col0 + wn * 64 + j * 32 + l5;
            float bv = act ? bias[c] : 0.f;
#pragma unroll
            for (int reg = 0; reg < 16; reg++) {
                int rrow = rbase + (reg & 3) + 8 * (reg >> 2);
                float v = acc[i][j][reg];
                if (act) v = fmaxf(v + bv, 0.f);
                C[(size_t)rrow * F_OUT + c] = f2bf(v);
            }
        }
    }
}

// ---------------- node-parallel mean-pool ----------------
__global__ __launch_bounds__(256) void k_pool(const unsigned short* __restrict__ h,
                                              const int* __restrict__ batch,
                                              const int* __restrict__ gstart,
                                              float* __restrict__ out) {
    const int r0 = blockIdx.x * 64;
    const int rowsub = threadIdx.x >> 7;           // 0..1
    const int c = (threadIdx.x & 127) * 8;         // full 1024-col row
    const int rend = min(r0 + 64, N_NODES);
    int row = r0 + rowsub;
    if (row >= rend) return;

    float a[8] = {};
    int gcur = batch[row];
    for (; row < rend; row += 2) {
        int g = batch[row];
        if (g != gcur) {
            float inv = 1.0f / (float)max(gstart[gcur + 1] - gstart[gcur], 1);
#pragma unroll
            for (int i = 0; i < 8; i++) {
                atomicAdd(&out[(size_t)gcur * F_OUT + c + i], a[i] * inv);
                a[i] = 0.f;
            }
            gcur = g;
        }
        ushort8v v = *(const ushort8v*)&h[(size_t)row * F_OUT + c];
#pragma unroll
        for (int i = 0; i < 8; i++) a[i] += bf2f(v[i]);
    }
    float inv = 1.0f / (float)max(gstart[gcur + 1] - gstart[gcur], 1);
#pragma unroll
    for (int i = 0; i < 8; i++)
        atomicAdd(&out[(size_t)gcur * F_OUT + c + i], a[i] * inv);
}

// ---------------- launch ----------------
extern "C" void kernel_launch(void* const* d_in, const int* in_sizes, int n_in,
                              void* d_out, int out_size, void* d_ws, size_t ws_size,
                              hipStream_t stream) {
    const float* x    = (const float*)d_in[0];
    const int* ei     = (const int*)d_in[1];
    const float* ew   = (const float*)d_in[2];
    const int* batch  = (const int*)d_in[3];
    const float* W1   = (const float*)d_in[4];
    const float* b1   = (const float*)d_in[5];
    const float* W2   = (const float*)d_in[6];
    const float* b2   = (const float*)d_in[7];
    float* out = (float*)d_out;

    const int* src = ei;
    const int* dst = ei + N_EDGES;

    char* ws = (char*)d_ws;
    const size_t SZ_XB  = (size_t)N_PAD * F_IN * 2;    // 21.0 MB
    const size_t SZ_AX  = (size_t)N_PAD * F_IN * 2;    // 21.0 MB
    const size_t SZ_WT1 = (size_t)F_OUT * F_IN * 2;    //  1 MB
    const size_t SZ_WT2 = (size_t)F_OUT * F_OUT * 2;   //  2 MB
    const size_t SZ_B   = (size_t)N_PAD * F_OUT * 2;   // 41.9 MB
    unsigned short* xb  = (unsigned short*)(ws);
    unsigned short* ax  = (unsigned short*)(ws + SZ_XB);
    unsigned short* Wt1 = (unsigned short*)(ws + SZ_XB + SZ_AX);
    unsigned short* Wt2 = (unsigned short*)(ws + SZ_XB + SZ_AX + SZ_WT1);
    unsigned short* h1  = (unsigned short*)(ws + SZ_XB + SZ_AX + SZ_WT1 + SZ_WT2);
    unsigned short* xw2 = (unsigned short*)(ws + SZ_XB + SZ_AX + SZ_WT1 + SZ_WT2 + SZ_B);
    unsigned short* h2  = (unsigned short*)(ws);       // aliases xb/ax (dead in phase B)
    size_t off = SZ_XB + SZ_AX + SZ_WT1 + SZ_WT2 + 2 * SZ_B;
    auto alloc = [&](size_t bytes) -> void* {
        void* p = ws + off;
        off += (bytes + 255) & ~(size_t)255;
        return p;
    };
    float*        deg    = (float*)       alloc((size_t)N_NODES * 4);
    int*          cursor = (int*)         alloc((size_t)N_NODES * 4);
    unsigned int* csre   = (unsigned int*)alloc((size_t)N_NODES * ESTRIDE * 4);  // 5.12 MB
    int*          gstart = (int*)         alloc((size_t)(N_GRAPHS + 1) * 4);

    // 1. setup (deg=1, cursor=0, out=0, gstart)
    k_setup<<<(N_GRAPHS * F_OUT + 255) / 256, 256, 0, stream>>>(deg, cursor, out, batch, gstart);
    // 2. fat pre-pass: deg atomics + both W transposes + x->bf16
    k_pre<<<NB_E + NB_WT + NB_CX, 256, 0, stream>>>(dst, ew, deg, W1, Wt1, W2, Wt2, x, xb);
    // 3. packed direct-slot edge table (scan eliminated)
    k_fill<<<NB_E, 256, 0, stream>>>(src, dst, ew, deg, cursor, csre);
    // 4. layer-1 aggregation (X-space, reassociated)
    k_aggr_slab<<<(N_PAD / 8) * 8, 64, 0, stream>>>(xb, deg, cursor, csre, ax, F_IN);
    // 5/6. GEMMs (BK=64)
    const int gemm_blocks = (N_PAD / 128) * (F_OUT / 128);   // 1280
    k_gemm_bf16<<<gemm_blocks, 256, 0, stream>>>(ax, Wt1, h1, F_IN, b1, 1);
    k_gemm_bf16<<<gemm_blocks, 256, 0, stream>>>(h1, Wt2, xw2, F_OUT, (const float*)nullptr, 0);
    // 7. layer-2 dual-pass aggregation + bias + relu -> h2
    k_aggr_dual<<<(N_NODES / 8) * 8, 64, 0, stream>>>(xw2, deg, cursor, csre, b2, h2);
    // 8. pool (node-parallel)
    k_pool<<<(N_NODES + 63) / 64, 256, 0, stream>>>(h2, batch, gstart, out);
}